// Round 4
// baseline (1175.690 us; speedup 1.0000x reference)
//
#include <hip/hip_runtime.h>
#include <cstdint>
#include <cstddef>

typedef unsigned short u16;
typedef __attribute__((ext_vector_type(4))) float f32x4;
typedef __attribute__((ext_vector_type(8))) __bf16 bf16x8;
typedef __attribute__((ext_vector_type(8))) unsigned short u16x8;

#define B_    2
#define L_    2048
#define DIM_  2048
#define H_    16
#define HD_   128
#define NQKV_ 6144
#define M_    4096   // B_*L_

__device__ __forceinline__ float b2f(u16 h) {
  union { unsigned u; float f; } v; v.u = ((unsigned)h) << 16; return v.f;
}
__device__ __forceinline__ u16 f2bf(float f) {
  unsigned u = __float_as_uint(f);
  u += 0x7fffu + ((u >> 16) & 1u);   // RNE
  return (u16)(u >> 16);
}
__device__ __forceinline__ f32x4 mfma16(bf16x8 a, bf16x8 b, f32x4 c) {
  return __builtin_amdgcn_mfma_f32_16x16x32_bf16(a, b, c, 0, 0, 0);
}
__device__ __forceinline__ bf16x8 as_bf(u16x8 v) {
  union { u16x8 u; bf16x8 b; } c; c.u = v; return c.b;
}

// Runtime dtype probe: look at the first 64 EVEN-indexed u16 of x.
// bf16 stream -> N(0,1) values, exponent byte in [100,135] ~always.
// f32 stream  -> even u16 = low mantissa bits, exponent byte ~uniform (hit ~14%).
__device__ __forceinline__ bool is_f32(const u16* p) {
  int cnt = 0;
  #pragma unroll
  for (int i = 0; i < 64; ++i) {
    int e = (p[2 * i] >> 7) & 0xff;
    cnt += (e >= 100 && e <= 135) ? 1 : 0;
  }
  return cnt < 32;
}

__device__ __forceinline__ u16x8 cvt8(const float* p) {
  u16x8 r;
  #pragma unroll
  for (int j = 0; j < 8; ++j) r[j] = f2bf(p[j]);
  return r;
}

// ---------------------------------------------------------------------------
// GEMM: C[M,N] = A[M,K] * B[K,N]  (B row-major K x N — NO pre-transpose;
// B tile is transposed into LDS during staging via scalar stores).
// A and B are raw inputs in MODE 1 (dual dtype); in MODE 2 A is bf16 (Ao).
// MODE 1: scatter epilogue into Q/K/V (B,H,L,D) buffers (D0=Q, D1=K, D2=V)
// MODE 2: bias-add epilogue (dual-dtype bias), dual-dtype store to outp
// ---------------------------------------------------------------------------
template <int MODE>
__global__ __launch_bounds__(256) void gemm_bt(
    const void* __restrict__ Ap, const void* __restrict__ Bp,
    u16* __restrict__ D0, u16* __restrict__ D1, u16* __restrict__ D2,
    const void* __restrict__ biasp, void* __restrict__ outp,
    const u16* __restrict__ probe, int M, int N, int K) {
  __shared__ __align__(16) u16 Alds[128 * 32];   // [m][k]
  __shared__ __align__(16) u16 Blds[128 * 32];   // [n][k]  (transposed tile)
  const bool f32in = is_f32(probe);
  const int tid = threadIdx.x;
  const int wave = tid >> 6, lane = tid & 63;
  const int wm = wave >> 1, wn = wave & 1;
  const int ln = lane & 15, qd = lane >> 4;
  const int m0 = blockIdx.y * 128, n0 = blockIdx.x * 128;

  f32x4 acc[4][4];
  #pragma unroll
  for (int i = 0; i < 4; ++i)
    #pragma unroll
    for (int j = 0; j < 4; ++j) acc[i][j] = (f32x4){0.f, 0.f, 0.f, 0.f};

  for (int k0 = 0; k0 < K; k0 += 32) {
    u16x8 va[2], vb[2];
    #pragma unroll
    for (int j = 0; j < 2; ++j) {
      int q = j * 256 + tid;
      // A chunk: tile 128 rows(m) x 32 cols(k), 4 chunks/row
      int ar = q >> 2, ac = (q & 3) * 8;
      if (MODE == 1 && f32in)
        va[j] = cvt8(&((const float*)Ap)[(size_t)(m0 + ar) * K + k0 + ac]);
      else
        va[j] = *(const u16x8*)&((const u16*)Ap)[(size_t)(m0 + ar) * K + k0 + ac];
      // B chunk: tile 32 rows(k) x 128 cols(n), 16 chunks/row
      int br = q >> 4, bc = (q & 15) * 8;
      if (f32in)
        vb[j] = cvt8(&((const float*)Bp)[(size_t)(k0 + br) * N + n0 + bc]);
      else
        vb[j] = *(const u16x8*)&((const u16*)Bp)[(size_t)(k0 + br) * N + n0 + bc];
    }
    __syncthreads();                 // prev iter's fragment ds_reads done
    #pragma unroll
    for (int j = 0; j < 2; ++j) {
      int q = j * 256 + tid;
      int ar = q >> 2, ac = (q & 3) * 8;
      *(u16x8*)&Alds[ar * 32 + ac] = va[j];
      int br = q >> 4, bc = (q & 15) * 8;
      #pragma unroll
      for (int e = 0; e < 8; ++e) Blds[(bc + e) * 32 + br] = vb[j][e];
    }
    __syncthreads();
    bf16x8 af[4], bfr[4];
    #pragma unroll
    for (int mi = 0; mi < 4; ++mi)
      af[mi] = *(const bf16x8*)&Alds[(wm * 64 + mi * 16 + ln) * 32 + qd * 8];
    #pragma unroll
    for (int ni = 0; ni < 4; ++ni)
      bfr[ni] = *(const bf16x8*)&Blds[(wn * 64 + ni * 16 + ln) * 32 + qd * 8];
    #pragma unroll
    for (int mi = 0; mi < 4; ++mi)
      #pragma unroll
      for (int ni = 0; ni < 4; ++ni)
        acc[mi][ni] = mfma16(af[mi], bfr[ni], acc[mi][ni]);
  }

  // epilogue: C/D layout col=lane&15, row=quad*4+reg  [m89-verified]
  #pragma unroll
  for (int mi = 0; mi < 4; ++mi) {
    #pragma unroll
    for (int ni = 0; ni < 4; ++ni) {
      #pragma unroll
      for (int r = 0; r < 4; ++r) {
        int row = m0 + wm * 64 + mi * 16 + qd * 4 + r;
        int col = n0 + wn * 64 + ni * 16 + ln;
        float v = acc[mi][ni][r];
        if (MODE == 2) {
          v += f32in ? ((const float*)biasp)[col] : b2f(((const u16*)biasp)[col]);
          if (f32in) ((float*)outp)[(size_t)row * N + col] = v;
          else       ((u16*)outp)[(size_t)row * N + col] = f2bf(v);
        } else {
          int t = col >> 11;           // 0=q, 1=k, 2=v
          int hc = col & 2047;
          int h = hc >> 7, d = hc & 127;
          int b = row >> 11, l = row & 2047;
          u16* dst = (t == 0) ? D0 : ((t == 1) ? D1 : D2);
          dst[((size_t)(b * H_ + h) * L_ + l) * HD_ + d] = f2bf(v);
        }
      }
    }
  }
}

// ---------------------------------------------------------------------------
// In-place rotary on Q and K, layout (B*H, L, 128). block = 128 thr:
// t<64 handles Q pair (d, d+64), t>=64 handles K pair. blockIdx = bh*L + l.
// cos/sin are raw inputs -> dual dtype.
// ---------------------------------------------------------------------------
__global__ __launch_bounds__(128) void rotary_k(
    u16* __restrict__ Q, u16* __restrict__ Kb,
    const void* __restrict__ cs, const void* __restrict__ sn,
    const u16* __restrict__ probe) {
  const bool f32in = is_f32(probe);
  int bid = blockIdx.x;
  int l = bid & (L_ - 1);
  int t = threadIdx.x;
  int d = t & 63;
  u16* P = (t < 64) ? Q : Kb;
  size_t base = (size_t)bid * HD_;
  int ci = l * 64 + d;
  float c = f32in ? ((const float*)cs)[ci] : b2f(((const u16*)cs)[ci]);
  float s = f32in ? ((const float*)sn)[ci] : b2f(((const u16*)sn)[ci]);
  float x1 = b2f(P[base + d]), x2 = b2f(P[base + d + 64]);
  P[base + d] = f2bf(x1 * c - x2 * s);
  P[base + d + 64] = f2bf(x2 * c + x1 * s);
}

// ---------------------------------------------------------------------------
// Flash attention. grid (16 qtiles, 32 bh), 256 thr (4 waves).
// Q,K,V all (B*H, L, 128) bf16. BM=128, BN=64 keys/iter. V tile is
// transposed into Vlds[d][key] during staging (scalar stores).
// Wave w owns q-rows [w*32, w*32+32). Online softmax stats replicated across
// each quad's 16 lanes (rows = quad*4+reg, C/D layout).
// ---------------------------------------------------------------------------
__global__ __launch_bounds__(256) void attn_k(
    const u16* __restrict__ Q, const u16* __restrict__ Kb,
    const u16* __restrict__ V, u16* __restrict__ Ao) {
  __shared__ __align__(16) u16 lds[24576];     // 48 KB
  u16* Klds = lds;               // [64 keys][128 d]
  u16* Vlds = lds + 8192;        // [128 d][64 keys]
  u16* Plds = lds + 16384;       // [128 q][64 keys]
  const int tid = threadIdx.x;
  const int w = tid >> 6, lane = tid & 63;
  const int ln = lane & 15, qd = lane >> 4;
  const int qt = blockIdx.x, bh = blockIdx.y;
  const int b = bh >> 4, h = bh & 15;
  const size_t slab = (size_t)bh * (L_ * HD_);

  // stage Q tile (contiguous 16384 elems) into lds[0..16384)
  {
    u16x8 vq[8];
    #pragma unroll
    for (int j = 0; j < 8; ++j) {
      int f = (j * 256 + tid) * 8;
      vq[j] = *(const u16x8*)&Q[slab + (size_t)qt * 16384 + f];
    }
    #pragma unroll
    for (int j = 0; j < 8; ++j) {
      int f = (j * 256 + tid) * 8;
      *(u16x8*)&lds[f] = vq[j];
    }
  }
  __syncthreads();
  bf16x8 aq[2][4];                         // Q fragments in registers
  #pragma unroll
  for (int mi = 0; mi < 2; ++mi)
    #pragma unroll
    for (int kc = 0; kc < 4; ++kc)
      aq[mi][kc] = *(const bf16x8*)&lds[(w * 32 + mi * 16 + ln) * 128 + kc * 32 + qd * 8];

  f32x4 o[2][8];
  #pragma unroll
  for (int i = 0; i < 2; ++i)
    #pragma unroll
    for (int j = 0; j < 8; ++j) o[i][j] = (f32x4){0.f, 0.f, 0.f, 0.f};
  float mst[2][4], lst[2][4];
  #pragma unroll
  for (int i = 0; i < 2; ++i)
    #pragma unroll
    for (int r = 0; r < 4; ++r) { mst[i][r] = -1e30f; lst[i][r] = 0.f; }
  const float SC = 0.12751744f;            // (1/sqrt(128)) * log2(e)

  for (int it = 0; it < 32; ++it) {
    u16x8 vk[4], vv[4];
    #pragma unroll
    for (int j = 0; j < 4; ++j) {
      int q = j * 256 + tid;
      // K tile: 64 rows(key) x 128 cols(d), contiguous copy
      vk[j] = *(const u16x8*)&Kb[slab + (size_t)it * 8192 + q * 8];
      // V tile: rows key, cols d; will transpose into Vlds[d][key]
      int key = q >> 4, d0 = (q & 15) * 8;
      vv[j] = *(const u16x8*)&V[slab + (size_t)(it * 64 + key) * 128 + d0];
    }
    __syncthreads();                       // prev iter's LDS reads done
    #pragma unroll
    for (int j = 0; j < 4; ++j) {
      int q = j * 256 + tid;
      *(u16x8*)&Klds[q * 8] = vk[j];
      int key = q >> 4, d0 = (q & 15) * 8;
      #pragma unroll
      for (int e = 0; e < 8; ++e) Vlds[(d0 + e) * 64 + key] = vv[j][e];
    }
    __syncthreads();

    // S = Q K^T  (raw dot products; scale folded into softmax)
    f32x4 sa[2][4];
    #pragma unroll
    for (int i = 0; i < 2; ++i)
      #pragma unroll
      for (int j = 0; j < 4; ++j) sa[i][j] = (f32x4){0.f, 0.f, 0.f, 0.f};
    #pragma unroll
    for (int kc = 0; kc < 4; ++kc) {
      bf16x8 bk[4];
      #pragma unroll
      for (int ni = 0; ni < 4; ++ni)
        bk[ni] = *(const bf16x8*)&Klds[(ni * 16 + ln) * 128 + kc * 32 + qd * 8];
      #pragma unroll
      for (int mi = 0; mi < 2; ++mi)
        #pragma unroll
        for (int ni = 0; ni < 4; ++ni)
          sa[mi][ni] = mfma16(aq[mi][kc], bk[ni], sa[mi][ni]);
    }

    // online softmax per q-row; row r of tile lives on one quad (16 lanes)
    #pragma unroll
    for (int mi = 0; mi < 2; ++mi) {
      #pragma unroll
      for (int r = 0; r < 4; ++r) {
        float tmax = -1e30f;
        #pragma unroll
        for (int ni = 0; ni < 4; ++ni) tmax = fmaxf(tmax, sa[mi][ni][r]);
        tmax *= SC;
        tmax = fmaxf(tmax, __shfl_xor(tmax, 1));
        tmax = fmaxf(tmax, __shfl_xor(tmax, 2));
        tmax = fmaxf(tmax, __shfl_xor(tmax, 4));
        tmax = fmaxf(tmax, __shfl_xor(tmax, 8));
        float mnew = fmaxf(mst[mi][r], tmax);
        float alpha = exp2f(mst[mi][r] - mnew);
        float p[4], rs = 0.f;
        #pragma unroll
        for (int ni = 0; ni < 4; ++ni) {
          p[ni] = exp2f(sa[mi][ni][r] * SC - mnew);
          rs += p[ni];
        }
        rs += __shfl_xor(rs, 1);
        rs += __shfl_xor(rs, 2);
        rs += __shfl_xor(rs, 4);
        rs += __shfl_xor(rs, 8);
        lst[mi][r] = lst[mi][r] * alpha + rs;
        mst[mi][r] = mnew;
        #pragma unroll
        for (int di = 0; di < 8; ++di) o[mi][di][r] *= alpha;
        #pragma unroll
        for (int ni = 0; ni < 4; ++ni)   // P in A-operand layout [q][key]
          Plds[(w * 32 + mi * 16 + qd * 4 + r) * 64 + ni * 16 + ln] = f2bf(p[ni]);
      }
    }

    __syncthreads();                       // P writes visible

    // O += P V
    #pragma unroll
    for (int kc = 0; kc < 2; ++kc) {
      bf16x8 ap[2];
      #pragma unroll
      for (int mi = 0; mi < 2; ++mi)
        ap[mi] = *(const bf16x8*)&Plds[(w * 32 + mi * 16 + ln) * 64 + kc * 32 + qd * 8];
      #pragma unroll
      for (int di = 0; di < 8; ++di) {
        bf16x8 bv = *(const bf16x8*)&Vlds[(di * 16 + ln) * 64 + kc * 32 + qd * 8];
        o[0][di] = mfma16(ap[0], bv, o[0][di]);
        o[1][di] = mfma16(ap[1], bv, o[1][di]);
      }
    }
  }

  // epilogue: normalize and write attn_out (B, L, H*D) row-major (bf16)
  #pragma unroll
  for (int mi = 0; mi < 2; ++mi) {
    #pragma unroll
    for (int r = 0; r < 4; ++r) {
      float inv = 1.0f / lst[mi][r];
      int lrow = qt * 128 + w * 32 + mi * 16 + qd * 4 + r;
      size_t orow = ((size_t)b * L_ + lrow) * DIM_ + (size_t)h * HD_;
      #pragma unroll
      for (int di = 0; di < 8; ++di)
        Ao[orow + di * 16 + ln] = f2bf(o[mi][di][r] * inv);
    }
  }
}

// ---------------------------------------------------------------------------
extern "C" void kernel_launch(void* const* d_in, const int* in_sizes, int n_in,
                              void* d_out, int out_size, void* d_ws, size_t ws_size,
                              hipStream_t stream) {
  const void* x    = d_in[0];
  const void* cs   = d_in[1];
  const void* sn   = d_in[2];
  const void* wqkv = d_in[3];
  const void* wout = d_in[4];
  const void* bias = d_in[5];
  const u16* probe = (const u16*)d_in[0];
  u16* ws = (u16*)d_ws;

  // workspace: 4 x 8,388,608 u16 = 67.1 MB total
  u16* Qb   = ws;                  // (B*H, L, 128)
  u16* Kbuf = Qb + 8388608;
  u16* Vbuf = Kbuf + 8388608;      // (B*H, L, 128) — no transpose copy
  u16* Ao   = Vbuf + 8388608;      // (B, L, 2048)

  gemm_bt<1><<<dim3(48, 32), 256, 0, stream>>>(
      x, wqkv, Qb, Kbuf, Vbuf, nullptr, nullptr, probe, M_, NQKV_, DIM_);
  rotary_k<<<dim3(65536), 128, 0, stream>>>(Qb, Kbuf, cs, sn, probe);
  attn_k<<<dim3(16, 32), 256, 0, stream>>>(Qb, Kbuf, Vbuf, Ao);
  gemm_bt<2><<<dim3(16, 32), 256, 0, stream>>>(
      Ao, wout, nullptr, nullptr, nullptr, bias, d_out, probe, M_, DIM_, DIM_);
}

// Round 5
// 638.682 us; speedup vs baseline: 1.8408x; 1.8408x over previous
//
#include <hip/hip_runtime.h>
#include <cstdint>
#include <cstddef>

typedef unsigned short u16;
typedef __attribute__((ext_vector_type(4))) float f32x4;
typedef __attribute__((ext_vector_type(8))) __bf16 bf16x8;
typedef __attribute__((ext_vector_type(8))) unsigned short u16x8;

#define B_    2
#define L_    2048
#define DIM_  2048
#define H_    16
#define HD_   128
#define NQKV_ 6144
#define M_    4096   // B_*L_

__device__ __forceinline__ float b2f(u16 h) {
  union { unsigned u; float f; } v; v.u = ((unsigned)h) << 16; return v.f;
}
__device__ __forceinline__ u16 f2bf(float f) {
  unsigned u = __float_as_uint(f);
  u += 0x7fffu + ((u >> 16) & 1u);   // RNE
  return (u16)(u >> 16);
}
__device__ __forceinline__ f32x4 mfma16(bf16x8 a, bf16x8 b, f32x4 c) {
  return __builtin_amdgcn_mfma_f32_16x16x32_bf16(a, b, c, 0, 0, 0);
}
__device__ __forceinline__ u16x8 cvt8(const float* p) {
  u16x8 r;
  #pragma unroll
  for (int j = 0; j < 8; ++j) r[j] = f2bf(p[j]);
  return r;
}

// ---------------------------------------------------------------------------
// GEMM: C[M,N] = A[M,K] * B[K,N], B row-major f32 (weights).
// B tile (32k x 128n) is transposed during staging at REGISTER level:
// thread owns (n-pair, k-octet): 8 coalesced dwordx2 f32 loads -> cvt ->
// two b128 stores into Blds[n][k] stride 40 (16B-aligned, banks spread).
// MODE 1: A = x f32; scatter epilogue into Q/K/V (B*H,L,D) bf16 buffers.
// MODE 2: A = Ao bf16; bias(f32)-add epilogue, f32 row-major store.
// ---------------------------------------------------------------------------
template <int MODE>
__global__ __launch_bounds__(256) void gemm_f(
    const void* __restrict__ Ap, const float* __restrict__ Bw,
    u16* __restrict__ D0, u16* __restrict__ D1, u16* __restrict__ D2,
    const float* __restrict__ bias, float* __restrict__ outp,
    int M, int N, int K) {
  __shared__ __align__(16) u16 Alds[128 * 32];   // [m][k]
  __shared__ __align__(16) u16 Blds[128 * 40];   // [n][k], stride 40 (pad)
  const int tid = threadIdx.x;
  const int wave = tid >> 6, lane = tid & 63;
  const int wm = wave >> 1, wn = wave & 1;
  const int ln = lane & 15, qd = lane >> 4;
  const int m0 = blockIdx.y * 128, n0 = blockIdx.x * 128;
  const int p2 = tid & 63, oct = tid >> 6;       // B-staging: n-pair, k-octet
  const int nb = 2 * p2, kb = oct * 8;

  f32x4 acc[4][4];
  #pragma unroll
  for (int i = 0; i < 4; ++i)
    #pragma unroll
    for (int j = 0; j < 4; ++j) acc[i][j] = (f32x4){0.f, 0.f, 0.f, 0.f};

  for (int k0 = 0; k0 < K; k0 += 32) {
    // ---- global loads into registers (coalesced) ----
    u16x8 va[2];
    #pragma unroll
    for (int j = 0; j < 2; ++j) {
      int q = j * 256 + tid;
      int ar = q >> 2, ac = (q & 3) * 8;         // A tile 128m x 32k
      if (MODE == 1)
        va[j] = cvt8(&((const float*)Ap)[(size_t)(m0 + ar) * K + k0 + ac]);
      else
        va[j] = *(const u16x8*)&((const u16*)Ap)[(size_t)(m0 + ar) * K + k0 + ac];
    }
    float bl[8], bh[8];
    #pragma unroll
    for (int e = 0; e < 8; ++e) {
      const float* bp = &Bw[(size_t)(k0 + kb + e) * N + n0 + nb];
      bl[e] = bp[0]; bh[e] = bp[1];
    }
    __syncthreads();                 // prev iter's fragment ds_reads done
    // ---- LDS stores ----
    #pragma unroll
    for (int j = 0; j < 2; ++j) {
      int q = j * 256 + tid;
      int ar = q >> 2, ac = (q & 3) * 8;
      *(u16x8*)&Alds[ar * 32 + ac] = va[j];
    }
    {
      u16x8 lo, hi;
      #pragma unroll
      for (int e = 0; e < 8; ++e) { lo[e] = f2bf(bl[e]); hi[e] = f2bf(bh[e]); }
      *(u16x8*)&Blds[nb * 40 + kb] = lo;
      *(u16x8*)&Blds[(nb + 1) * 40 + kb] = hi;
    }
    __syncthreads();
    // ---- fragments + MFMA ----
    bf16x8 af[4], bfr[4];
    #pragma unroll
    for (int mi = 0; mi < 4; ++mi)
      af[mi] = *(const bf16x8*)&Alds[(wm * 64 + mi * 16 + ln) * 32 + qd * 8];
    #pragma unroll
    for (int ni = 0; ni < 4; ++ni)
      bfr[ni] = *(const bf16x8*)&Blds[(wn * 64 + ni * 16 + ln) * 40 + qd * 8];
    #pragma unroll
    for (int mi = 0; mi < 4; ++mi)
      #pragma unroll
      for (int ni = 0; ni < 4; ++ni)
        acc[mi][ni] = mfma16(af[mi], bfr[ni], acc[mi][ni]);
  }

  // epilogue: C/D layout col=lane&15, row=quad*4+reg  [m89-verified]
  #pragma unroll
  for (int mi = 0; mi < 4; ++mi) {
    #pragma unroll
    for (int ni = 0; ni < 4; ++ni) {
      #pragma unroll
      for (int r = 0; r < 4; ++r) {
        int row = m0 + wm * 64 + mi * 16 + qd * 4 + r;
        int col = n0 + wn * 64 + ni * 16 + ln;
        float v = acc[mi][ni][r];
        if (MODE == 2) {
          outp[(size_t)row * N + col] = v + bias[col];
        } else {
          int t = col >> 11;           // 0=q, 1=k, 2=v
          int hc = col & 2047;
          int h = hc >> 7, d = hc & 127;
          int b = row >> 11, l = row & 2047;
          u16* dst = (t == 0) ? D0 : ((t == 1) ? D1 : D2);
          dst[((size_t)(b * H_ + h) * L_ + l) * HD_ + d] = f2bf(v);
        }
      }
    }
  }
}

// ---------------------------------------------------------------------------
// In-place rotary on Q and K, layout (B*H, L, 128). block = 128 thr:
// t<64 handles Q pair (d, d+64), t>=64 handles K pair. blockIdx = bh*L + l.
// cos/sin are f32 inputs.
// ---------------------------------------------------------------------------
__global__ __launch_bounds__(128) void rotary_k(
    u16* __restrict__ Q, u16* __restrict__ Kb,
    const float* __restrict__ cs, const float* __restrict__ sn) {
  int bid = blockIdx.x;
  int l = bid & (L_ - 1);
  int t = threadIdx.x;
  int d = t & 63;
  u16* P = (t < 64) ? Q : Kb;
  size_t base = (size_t)bid * HD_;
  int ci = l * 64 + d;
  float c = cs[ci], s = sn[ci];
  float x1 = b2f(P[base + d]), x2 = b2f(P[base + d + 64]);
  P[base + d] = f2bf(x1 * c - x2 * s);
  P[base + d + 64] = f2bf(x2 * c + x1 * s);
}

// ---------------------------------------------------------------------------
// Flash attention. grid (16 qtiles, 32 bh), 256 thr (4 waves).
// Q,K,V all (B*H, L, 128) bf16. BM=128, BN=64 keys/iter.
// V tile transposed at REGISTER level during staging: thread owns
// (d-pair, key-octet): 8 coalesced dword loads -> two b128 stores into
// Vlds[d][key] stride 72 (aligned, banks spread). Plds stride 72 likewise.
// Wave w owns q-rows [w*32, w*32+32). Online softmax stats replicated across
// each quad's 16 lanes (rows = quad*4+reg, C/D layout).
// ---------------------------------------------------------------------------
__global__ __launch_bounds__(256) void attn_k(
    const u16* __restrict__ Q, const u16* __restrict__ Kb,
    const u16* __restrict__ V, u16* __restrict__ Ao) {
  __shared__ __align__(16) u16 lds[26624];     // 52 KB
  u16* Klds = lds;               // [64 keys][128 d]
  u16* Vlds = lds + 8192;        // [128 d][72], keys 0..63 used
  u16* Plds = lds + 17408;       // [128 q][72], keys 0..63 used
  const int tid = threadIdx.x;
  const int w = tid >> 6, lane = tid & 63;
  const int ln = lane & 15, qd = lane >> 4;
  const int qt = blockIdx.x, bh = blockIdx.y;
  const int b = bh >> 4, h = bh & 15;
  const size_t slab = (size_t)bh * (L_ * HD_);
  const int vp = tid & 63, vd0 = 2 * vp;       // V staging: d-pair

  // stage Q tile (contiguous 16384 elems) into lds[0..16384)
  {
    u16x8 vq[8];
    #pragma unroll
    for (int j = 0; j < 8; ++j) {
      int f = (j * 256 + tid) * 8;
      vq[j] = *(const u16x8*)&Q[slab + (size_t)qt * 16384 + f];
    }
    #pragma unroll
    for (int j = 0; j < 8; ++j) {
      int f = (j * 256 + tid) * 8;
      *(u16x8*)&lds[f] = vq[j];
    }
  }
  __syncthreads();
  bf16x8 aq[2][4];                         // Q fragments in registers
  #pragma unroll
  for (int mi = 0; mi < 2; ++mi)
    #pragma unroll
    for (int kc = 0; kc < 4; ++kc)
      aq[mi][kc] = *(const bf16x8*)&lds[(w * 32 + mi * 16 + ln) * 128 + kc * 32 + qd * 8];

  f32x4 o[2][8];
  #pragma unroll
  for (int i = 0; i < 2; ++i)
    #pragma unroll
    for (int j = 0; j < 8; ++j) o[i][j] = (f32x4){0.f, 0.f, 0.f, 0.f};
  float mst[2][4], lst[2][4];
  #pragma unroll
  for (int i = 0; i < 2; ++i)
    #pragma unroll
    for (int r = 0; r < 4; ++r) { mst[i][r] = -1e30f; lst[i][r] = 0.f; }
  const float SC = 0.12751744f;            // (1/sqrt(128)) * log2(e)

  for (int it = 0; it < 32; ++it) {
    // ---- global loads into registers (coalesced) ----
    u16x8 vk[4];
    #pragma unroll
    for (int j = 0; j < 4; ++j)
      vk[j] = *(const u16x8*)&Kb[slab + (size_t)it * 8192 + (j * 256 + tid) * 8];
    unsigned vv[2][8];                     // V: d-pair x key-octet, 2 passes
    #pragma unroll
    for (int n2 = 0; n2 < 2; ++n2) {
      int key0 = ((tid >> 6) + n2 * 4) * 8;
      #pragma unroll
      for (int e = 0; e < 8; ++e)
        vv[n2][e] = *(const unsigned*)&V[slab + (size_t)(it * 64 + key0 + e) * 128 + vd0];
    }
    __syncthreads();                       // prev iter's LDS reads done
    // ---- LDS stores ----
    #pragma unroll
    for (int j = 0; j < 4; ++j)
      *(u16x8*)&Klds[(j * 256 + tid) * 8] = vk[j];
    #pragma unroll
    for (int n2 = 0; n2 < 2; ++n2) {
      int key0 = ((tid >> 6) + n2 * 4) * 8;
      u16x8 lo, hi;
      #pragma unroll
      for (int e = 0; e < 8; ++e) {
        lo[e] = (u16)(vv[n2][e] & 0xffffu);
        hi[e] = (u16)(vv[n2][e] >> 16);
      }
      *(u16x8*)&Vlds[vd0 * 72 + key0] = lo;
      *(u16x8*)&Vlds[(vd0 + 1) * 72 + key0] = hi;
    }
    __syncthreads();

    // S = Q K^T  (raw dot products; scale folded into softmax)
    f32x4 sa[2][4];
    #pragma unroll
    for (int i = 0; i < 2; ++i)
      #pragma unroll
      for (int j = 0; j < 4; ++j) sa[i][j] = (f32x4){0.f, 0.f, 0.f, 0.f};
    #pragma unroll
    for (int kc = 0; kc < 4; ++kc) {
      bf16x8 bk[4];
      #pragma unroll
      for (int ni = 0; ni < 4; ++ni)
        bk[ni] = *(const bf16x8*)&Klds[(ni * 16 + ln) * 128 + kc * 32 + qd * 8];
      #pragma unroll
      for (int mi = 0; mi < 2; ++mi)
        #pragma unroll
        for (int ni = 0; ni < 4; ++ni)
          sa[mi][ni] = mfma16(aq[mi][kc], bk[ni], sa[mi][ni]);
    }

    // online softmax per q-row; row r of tile lives on one quad (16 lanes)
    #pragma unroll
    for (int mi = 0; mi < 2; ++mi) {
      #pragma unroll
      for (int r = 0; r < 4; ++r) {
        float tmax = -1e30f;
        #pragma unroll
        for (int ni = 0; ni < 4; ++ni) tmax = fmaxf(tmax, sa[mi][ni][r]);
        tmax *= SC;
        tmax = fmaxf(tmax, __shfl_xor(tmax, 1));
        tmax = fmaxf(tmax, __shfl_xor(tmax, 2));
        tmax = fmaxf(tmax, __shfl_xor(tmax, 4));
        tmax = fmaxf(tmax, __shfl_xor(tmax, 8));
        float mnew = fmaxf(mst[mi][r], tmax);
        float alpha = exp2f(mst[mi][r] - mnew);
        float p[4], rs = 0.f;
        #pragma unroll
        for (int ni = 0; ni < 4; ++ni) {
          p[ni] = exp2f(sa[mi][ni][r] * SC - mnew);
          rs += p[ni];
        }
        rs += __shfl_xor(rs, 1);
        rs += __shfl_xor(rs, 2);
        rs += __shfl_xor(rs, 4);
        rs += __shfl_xor(rs, 8);
        lst[mi][r] = lst[mi][r] * alpha + rs;
        mst[mi][r] = mnew;
        #pragma unroll
        for (int di = 0; di < 8; ++di) o[mi][di][r] *= alpha;
        #pragma unroll
        for (int ni = 0; ni < 4; ++ni)   // P in A-operand layout [q][key]
          Plds[(w * 32 + mi * 16 + qd * 4 + r) * 72 + ni * 16 + ln] = f2bf(p[ni]);
      }
    }

    __syncthreads();                       // P writes visible

    // O += P V
    #pragma unroll
    for (int kc = 0; kc < 2; ++kc) {
      bf16x8 ap[2];
      #pragma unroll
      for (int mi = 0; mi < 2; ++mi)
        ap[mi] = *(const bf16x8*)&Plds[(w * 32 + mi * 16 + ln) * 72 + kc * 32 + qd * 8];
      #pragma unroll
      for (int di = 0; di < 8; ++di) {
        bf16x8 bv = *(const bf16x8*)&Vlds[(di * 16 + ln) * 72 + kc * 32 + qd * 8];
        o[0][di] = mfma16(ap[0], bv, o[0][di]);
        o[1][di] = mfma16(ap[1], bv, o[1][di]);
      }
    }
  }

  // epilogue: normalize and write attn_out (B, L, H*D) row-major (bf16)
  #pragma unroll
  for (int mi = 0; mi < 2; ++mi) {
    #pragma unroll
    for (int r = 0; r < 4; ++r) {
      float inv = 1.0f / lst[mi][r];
      int lrow = qt * 128 + w * 32 + mi * 16 + qd * 4 + r;
      size_t orow = ((size_t)b * L_ + lrow) * DIM_ + (size_t)h * HD_;
      #pragma unroll
      for (int di = 0; di < 8; ++di)
        Ao[orow + di * 16 + ln] = f2bf(o[mi][di][r] * inv);
    }
  }
}

// ---------------------------------------------------------------------------
extern "C" void kernel_launch(void* const* d_in, const int* in_sizes, int n_in,
                              void* d_out, int out_size, void* d_ws, size_t ws_size,
                              hipStream_t stream) {
  const float* x    = (const float*)d_in[0];
  const float* cs   = (const float*)d_in[1];
  const float* sn   = (const float*)d_in[2];
  const float* wqkv = (const float*)d_in[3];
  const float* wout = (const float*)d_in[4];
  const float* bias = (const float*)d_in[5];
  u16* ws = (u16*)d_ws;

  // workspace: 4 x 8,388,608 u16 = 67.1 MB (validated size)
  u16* Qb   = ws;                  // (B*H, L, 128) bf16
  u16* Kbuf = Qb + 8388608;
  u16* Vbuf = Kbuf + 8388608;
  u16* Ao   = Vbuf + 8388608;      // (B, L, 2048) bf16

  gemm_f<1><<<dim3(48, 32), 256, 0, stream>>>(
      x, wqkv, Qb, Kbuf, Vbuf, nullptr, nullptr, M_, NQKV_, DIM_);
  rotary_k<<<dim3(65536), 128, 0, stream>>>(Qb, Kbuf, cs, sn);
  attn_k<<<dim3(16, 32), 256, 0, stream>>>(Qb, Kbuf, Vbuf, Ao);
  gemm_f<2><<<dim3(16, 32), 256, 0, stream>>>(
      Ao, wout, nullptr, nullptr, nullptr, bias, (float*)d_out, M_, DIM_, DIM_);
}

// Round 6
// 556.026 us; speedup vs baseline: 2.1145x; 1.1487x over previous
//
#include <hip/hip_runtime.h>
#include <cstdint>
#include <cstddef>

typedef unsigned short u16;
typedef __attribute__((ext_vector_type(2))) unsigned short u16x2;
typedef __attribute__((ext_vector_type(4))) unsigned short u16x4;
typedef __attribute__((ext_vector_type(8))) unsigned short u16x8;
typedef __attribute__((ext_vector_type(4))) float f32x4;
typedef __attribute__((ext_vector_type(8))) __bf16 bf16x8;

#define B_    2
#define L_    2048
#define DIM_  2048
#define H_    16
#define HD_   128
#define NQKV_ 6144
#define M_    4096   // B_*L_

__device__ __forceinline__ float b2f(u16 h) {
  union { unsigned u; float f; } v; v.u = ((unsigned)h) << 16; return v.f;
}
__device__ __forceinline__ u16 f2bf(float f) {
  unsigned u = __float_as_uint(f);
  u += 0x7fffu + ((u >> 16) & 1u);   // RNE
  return (u16)(u >> 16);
}
__device__ __forceinline__ f32x4 mfma16(bf16x8 a, bf16x8 b, f32x4 c) {
  return __builtin_amdgcn_mfma_f32_16x16x32_bf16(a, b, c, 0, 0, 0);
}
__device__ __forceinline__ void async16(const void* g, void* l) {
  __builtin_amdgcn_global_load_lds(
      (const __attribute__((address_space(1))) unsigned*)g,
      (__attribute__((address_space(3))) unsigned*)l, 16, 0, 0);
}

// ---------------------------------------------------------------------------
// Pre-pass 1: straight f32 -> bf16 convert (x). 4 elems/thread.
// ---------------------------------------------------------------------------
__global__ __launch_bounds__(256) void cvt_bf16(
    const float* __restrict__ src, u16* __restrict__ dst) {
  int i = (blockIdx.x * 256 + threadIdx.x) * 4;
  f32x4 v = *(const f32x4*)&src[i];
  u16x4 o;
  #pragma unroll
  for (int j = 0; j < 4; ++j) o[j] = f2bf(v[j]);
  *(u16x4*)&dst[i] = o;
}

// ---------------------------------------------------------------------------
// Pre-pass 2: f32 (R x C) -> bf16 transposed (C x R). 64x64 LDS tile.
// ---------------------------------------------------------------------------
__global__ __launch_bounds__(256) void transpose_cvt(
    const float* __restrict__ src, u16* __restrict__ dst, int R, int C) {
  __shared__ u16 tile[64][66];
  int r0 = blockIdx.y * 64, c0 = blockIdx.x * 64;
  #pragma unroll
  for (int i = 0; i < 16; ++i) {
    int f = i * 256 + threadIdx.x;
    int r = f >> 6, c = f & 63;
    tile[r][c] = f2bf(src[(size_t)(r0 + r) * C + (c0 + c)]);
  }
  __syncthreads();
  #pragma unroll
  for (int i = 0; i < 8; ++i) {
    int f = i * 256 + threadIdx.x;
    int cr = f >> 5, rp = (f & 31) * 2;
    u16x2 v = {tile[rp][cr], tile[rp + 1][cr]};
    *(u16x2*)&dst[(size_t)(c0 + cr) * R + (r0 + rp)] = v;
  }
}

// ---------------------------------------------------------------------------
// m97-style GEMM: C[M,N] = A[M,K] * Bt[N,K]^T, all-bf16 inputs, pure
// async16 (global_load_lds dwordx4) staging. 128x128 tile, BK=32, 256 thr.
// MODE 1: scatter epilogue into Q/K/V (B*H,L,D) bf16 buffers
// MODE 2: bias(f32)-add epilogue, f32 row-major store
// ---------------------------------------------------------------------------
template <int MODE>
__global__ __launch_bounds__(256) void gemm_bt(
    const u16* __restrict__ A, const u16* __restrict__ Bt,
    u16* __restrict__ D0, u16* __restrict__ D1, u16* __restrict__ D2,
    const float* __restrict__ bias, float* __restrict__ outp,
    int M, int N, int K) {
  __shared__ __align__(16) u16 Alds[128 * 32];
  __shared__ __align__(16) u16 Blds[128 * 32];
  const int tid = threadIdx.x;
  const int wave = tid >> 6, lane = tid & 63;
  const int wm = wave >> 1, wn = wave & 1;
  const int ln = lane & 15, qd = lane >> 4;
  const int m0 = blockIdx.y * 128, n0 = blockIdx.x * 128;

  f32x4 acc[4][4];
  #pragma unroll
  for (int i = 0; i < 4; ++i)
    #pragma unroll
    for (int j = 0; j < 4; ++j) acc[i][j] = (f32x4){0.f, 0.f, 0.f, 0.f};

  for (int k0 = 0; k0 < K; k0 += 32) {
    __syncthreads();                     // prev iter's fragment ds_reads done
    #pragma unroll
    for (int j = 0; j < 2; ++j) {
      int f = (j * 256 + tid) * 8;       // flat elem in 128x32 tile
      int r = f >> 5, c = f & 31;
      async16(&A[(size_t)(m0 + r) * K + (k0 + c)], &Alds[j * 2048 + wave * 512]);
      async16(&Bt[(size_t)(n0 + r) * K + (k0 + c)], &Blds[j * 2048 + wave * 512]);
    }
    __syncthreads();                     // drains vmcnt before use
    bf16x8 af[4], bfr[4];
    #pragma unroll
    for (int mi = 0; mi < 4; ++mi)
      af[mi] = *(const bf16x8*)&Alds[(wm * 64 + mi * 16 + ln) * 32 + qd * 8];
    #pragma unroll
    for (int ni = 0; ni < 4; ++ni)
      bfr[ni] = *(const bf16x8*)&Blds[(wn * 64 + ni * 16 + ln) * 32 + qd * 8];
    #pragma unroll
    for (int mi = 0; mi < 4; ++mi)
      #pragma unroll
      for (int ni = 0; ni < 4; ++ni)
        acc[mi][ni] = mfma16(af[mi], bfr[ni], acc[mi][ni]);
  }

  // epilogue: C/D layout col=lane&15, row=quad*4+reg  [m89-verified]
  #pragma unroll
  for (int mi = 0; mi < 4; ++mi) {
    #pragma unroll
    for (int ni = 0; ni < 4; ++ni) {
      #pragma unroll
      for (int r = 0; r < 4; ++r) {
        int row = m0 + wm * 64 + mi * 16 + qd * 4 + r;
        int col = n0 + wn * 64 + ni * 16 + ln;
        float v = acc[mi][ni][r];
        if (MODE == 2) {
          outp[(size_t)row * N + col] = v + bias[col];
        } else {
          int t = col >> 11;           // 0=q, 1=k, 2=v
          int hc = col & 2047;
          int h = hc >> 7, d = hc & 127;
          int b = row >> 11, l = row & 2047;
          u16* dst = (t == 0) ? D0 : ((t == 1) ? D1 : D2);
          dst[((size_t)(b * H_ + h) * L_ + l) * HD_ + d] = f2bf(v);
        }
      }
    }
  }
}

// ---------------------------------------------------------------------------
// In-place rotary on Q and K, layout (B*H, L, 128). block = 128 thr:
// t<64 handles Q pair (d, d+64), t>=64 handles K pair. blockIdx = bh*L + l.
// ---------------------------------------------------------------------------
__global__ __launch_bounds__(128) void rotary_k(
    u16* __restrict__ Q, u16* __restrict__ Kb,
    const float* __restrict__ cs, const float* __restrict__ sn) {
  int bid = blockIdx.x;
  int l = bid & (L_ - 1);
  int t = threadIdx.x;
  int d = t & 63;
  u16* P = (t < 64) ? Q : Kb;
  size_t base = (size_t)bid * HD_;
  int ci = l * 64 + d;
  float c = cs[ci], s = sn[ci];
  float x1 = b2f(P[base + d]), x2 = b2f(P[base + d + 64]);
  P[base + d] = f2bf(x1 * c - x2 * s);
  P[base + d + 64] = f2bf(x2 * c + x1 * s);
}

// ---------------------------------------------------------------------------
// Flash attention. grid (16 qtiles, 32 bh), 256 thr (4 waves).
// Q,K,V all (B*H, L, 128) bf16. BM=128, BN=64 keys/iter.
// Q and K tiles staged via async16 (contiguous copies); V transposed at
// register level (dword d-pair loads -> two b128 rows into Vlds stride 72).
// Wave w owns q-rows [w*32, w*32+32). Online softmax stats replicated across
// each quad's 16 lanes (rows = quad*4+reg, C/D layout).
// ---------------------------------------------------------------------------
__global__ __launch_bounds__(256) void attn_k(
    const u16* __restrict__ Q, const u16* __restrict__ Kb,
    const u16* __restrict__ V, u16* __restrict__ Ao) {
  __shared__ __align__(16) u16 lds[26624];     // 52 KB
  u16* Klds = lds;               // [64 keys][128 d]
  u16* Vlds = lds + 8192;        // [128 d][72], keys 0..63 used
  u16* Plds = lds + 17408;       // [128 q][72], keys 0..63 used
  const int tid = threadIdx.x;
  const int w = tid >> 6, lane = tid & 63;
  const int ln = lane & 15, qd = lane >> 4;
  const int qt = blockIdx.x, bh = blockIdx.y;
  const int b = bh >> 4, h = bh & 15;
  const size_t slab = (size_t)bh * (L_ * HD_);
  const int vp = tid & 63, vd0 = 2 * vp;       // V staging: d-pair

  // stage Q tile (contiguous 32 KB) into lds[0..16384) via async16
  #pragma unroll
  for (int j = 0; j < 8; ++j) {
    int f = (j * 256 + tid) * 8;
    async16(&Q[slab + (size_t)qt * 16384 + f], &lds[j * 2048 + w * 512]);
  }
  __syncthreads();
  bf16x8 aq[2][4];                         // Q fragments in registers
  #pragma unroll
  for (int mi = 0; mi < 2; ++mi)
    #pragma unroll
    for (int kc = 0; kc < 4; ++kc)
      aq[mi][kc] = *(const bf16x8*)&lds[(w * 32 + mi * 16 + ln) * 128 + kc * 32 + qd * 8];

  f32x4 o[2][8];
  #pragma unroll
  for (int i = 0; i < 2; ++i)
    #pragma unroll
    for (int j = 0; j < 8; ++j) o[i][j] = (f32x4){0.f, 0.f, 0.f, 0.f};
  float mst[2][4], lst[2][4];
  #pragma unroll
  for (int i = 0; i < 2; ++i)
    #pragma unroll
    for (int r = 0; r < 4; ++r) { mst[i][r] = -1e30f; lst[i][r] = 0.f; }
  const float SC = 0.12751744f;            // (1/sqrt(128)) * log2(e)

  for (int it = 0; it < 32; ++it) {
    // V global loads -> regs (no LDS touch; before barrier for latency)
    unsigned vv[2][8];
    #pragma unroll
    for (int n2 = 0; n2 < 2; ++n2) {
      int key0 = ((tid >> 6) + n2 * 4) * 8;
      #pragma unroll
      for (int e = 0; e < 8; ++e)
        vv[n2][e] = *(const unsigned*)&V[slab + (size_t)(it * 64 + key0 + e) * 128 + vd0];
    }
    __syncthreads();                       // prev iter's LDS readers done
    // K tile via async16 (contiguous 16 KB)
    #pragma unroll
    for (int j = 0; j < 4; ++j) {
      int f = (j * 256 + tid) * 8;
      async16(&Kb[slab + (size_t)it * 8192 + f], &Klds[j * 2048 + w * 512]);
    }
    // V transpose stores
    #pragma unroll
    for (int n2 = 0; n2 < 2; ++n2) {
      int key0 = ((tid >> 6) + n2 * 4) * 8;
      u16x8 lo, hi;
      #pragma unroll
      for (int e = 0; e < 8; ++e) {
        lo[e] = (u16)(vv[n2][e] & 0xffffu);
        hi[e] = (u16)(vv[n2][e] >> 16);
      }
      *(u16x8*)&Vlds[vd0 * 72 + key0] = lo;
      *(u16x8*)&Vlds[(vd0 + 1) * 72 + key0] = hi;
    }
    __syncthreads();                       // drains vmcnt (K) + lgkm (V)

    // S = Q K^T  (raw dot products; scale folded into softmax)
    f32x4 sa[2][4];
    #pragma unroll
    for (int i = 0; i < 2; ++i)
      #pragma unroll
      for (int j = 0; j < 4; ++j) sa[i][j] = (f32x4){0.f, 0.f, 0.f, 0.f};
    #pragma unroll
    for (int kc = 0; kc < 4; ++kc) {
      bf16x8 bk[4];
      #pragma unroll
      for (int ni = 0; ni < 4; ++ni)
        bk[ni] = *(const bf16x8*)&Klds[(ni * 16 + ln) * 128 + kc * 32 + qd * 8];
      #pragma unroll
      for (int mi = 0; mi < 2; ++mi)
        #pragma unroll
        for (int ni = 0; ni < 4; ++ni)
          sa[mi][ni] = mfma16(aq[mi][kc], bk[ni], sa[mi][ni]);
    }

    // online softmax per q-row; row r of tile lives on one quad (16 lanes)
    #pragma unroll
    for (int mi = 0; mi < 2; ++mi) {
      #pragma unroll
      for (int r = 0; r < 4; ++r) {
        float tmax = -1e30f;
        #pragma unroll
        for (int ni = 0; ni < 4; ++ni) tmax = fmaxf(tmax, sa[mi][ni][r]);
        tmax *= SC;
        tmax = fmaxf(tmax, __shfl_xor(tmax, 1));
        tmax = fmaxf(tmax, __shfl_xor(tmax, 2));
        tmax = fmaxf(tmax, __shfl_xor(tmax, 4));
        tmax = fmaxf(tmax, __shfl_xor(tmax, 8));
        float mnew = fmaxf(mst[mi][r], tmax);
        float alpha = exp2f(mst[mi][r] - mnew);
        float p[4], rs = 0.f;
        #pragma unroll
        for (int ni = 0; ni < 4; ++ni) {
          p[ni] = exp2f(sa[mi][ni][r] * SC - mnew);
          rs += p[ni];
        }
        rs += __shfl_xor(rs, 1);
        rs += __shfl_xor(rs, 2);
        rs += __shfl_xor(rs, 4);
        rs += __shfl_xor(rs, 8);
        lst[mi][r] = lst[mi][r] * alpha + rs;
        mst[mi][r] = mnew;
        #pragma unroll
        for (int di = 0; di < 8; ++di) o[mi][di][r] *= alpha;
        #pragma unroll
        for (int ni = 0; ni < 4; ++ni)   // P in A-operand layout [q][key]
          Plds[(w * 32 + mi * 16 + qd * 4 + r) * 72 + ni * 16 + ln] = f2bf(p[ni]);
      }
    }

    __syncthreads();                       // P writes visible

    // O += P V
    #pragma unroll
    for (int kc = 0; kc < 2; ++kc) {
      bf16x8 ap[2];
      #pragma unroll
      for (int mi = 0; mi < 2; ++mi)
        ap[mi] = *(const bf16x8*)&Plds[(w * 32 + mi * 16 + ln) * 72 + kc * 32 + qd * 8];
      #pragma unroll
      for (int di = 0; di < 8; ++di) {
        bf16x8 bv = *(const bf16x8*)&Vlds[(di * 16 + ln) * 72 + kc * 32 + qd * 8];
        o[0][di] = mfma16(ap[0], bv, o[0][di]);
        o[1][di] = mfma16(ap[1], bv, o[1][di]);
      }
    }
  }

  // epilogue: normalize and write attn_out (B, L, H*D) row-major (bf16)
  #pragma unroll
  for (int mi = 0; mi < 2; ++mi) {
    #pragma unroll
    for (int r = 0; r < 4; ++r) {
      float inv = 1.0f / lst[mi][r];
      int lrow = qt * 128 + w * 32 + mi * 16 + qd * 4 + r;
      size_t orow = ((size_t)b * L_ + lrow) * DIM_ + (size_t)h * HD_;
      #pragma unroll
      for (int di = 0; di < 8; ++di)
        Ao[orow + di * 16 + ln] = f2bf(o[mi][di][r] * inv);
    }
  }
}

// ---------------------------------------------------------------------------
extern "C" void kernel_launch(void* const* d_in, const int* in_sizes, int n_in,
                              void* d_out, int out_size, void* d_ws, size_t ws_size,
                              hipStream_t stream) {
  const float* x    = (const float*)d_in[0];
  const float* cs   = (const float*)d_in[1];
  const float* sn   = (const float*)d_in[2];
  const float* wqkv = (const float*)d_in[3];
  const float* wout = (const float*)d_in[4];
  const float* bias = (const float*)d_in[5];
  u16* ws = (u16*)d_ws;

  // Workspace (u16 elems), 92.3 MB total with two time-multiplexed overlaps:
  //   wqkvT 12,582,912  (N=6144 x K=2048 bf16; REUSED for woutT after gemm1)
  //   xbfAo  8,388,608  (x_bf during gemm1; Ao after attn)
  //   Qb/Kbuf/Vbuf 3 x 8,388,608
  u16* wqkvT = ws;
  u16* woutT = ws;                        // same region, written after gemm1
  u16* xbfAo = wqkvT + 12582912;
  u16* Qb    = xbfAo + 8388608;
  u16* Kbuf  = Qb + 8388608;
  u16* Vbuf  = Kbuf + 8388608;

  cvt_bf16<<<dim3(8192), 256, 0, stream>>>(x, xbfAo);
  transpose_cvt<<<dim3(96, 32), 256, 0, stream>>>(wqkv, wqkvT, 2048, 6144);
  gemm_bt<1><<<dim3(48, 32), 256, 0, stream>>>(
      xbfAo, wqkvT, Qb, Kbuf, Vbuf, nullptr, nullptr, M_, NQKV_, DIM_);
  transpose_cvt<<<dim3(32, 32), 256, 0, stream>>>(wout, woutT, 2048, 2048);
  rotary_k<<<dim3(65536), 128, 0, stream>>>(Qb, Kbuf, cs, sn);
  attn_k<<<dim3(16, 32), 256, 0, stream>>>(Qb, Kbuf, Vbuf, xbfAo);
  gemm_bt<2><<<dim3(16, 32), 256, 0, stream>>>(
      xbfAo, woutT, nullptr, nullptr, nullptr, bias, (float*)d_out, M_, DIM_, DIM_);
}